// Round 6
// baseline (144.395 us; speedup 1.0000x reference)
//
#include <hip/hip_runtime.h>
#include <math.h>
#include <stdint.h>

#define NB 8
#define SEQ 1024
#define DMODEL 512
#define NH 8
#define HD 64
#define R_TOT (NB * SEQ)   // 8192 rows

typedef __attribute__((ext_vector_type(8))) short bf16x8;
typedef __attribute__((ext_vector_type(4))) float f32x4;

__device__ __forceinline__ short f2b(float x) {
    uint32_t u = __float_as_uint(x);
    u += 0x7FFF + ((u >> 16) & 1);          // round-to-nearest-even
    return (short)(u >> 16);
}
__device__ __forceinline__ float b2f(short s) {
    return __uint_as_float(((uint32_t)(uint16_t)s) << 16);
}
__device__ __forceinline__ uint32_t cvtpk_bf16(float lo, float hi) {
    uint32_t r;
    asm("v_cvt_pk_bf16_f32 %0, %1, %2" : "=v"(r) : "v"(lo), "v"(hi));
    return r;
}

#define GLD_LDS16(g, l)                                                        \
    __builtin_amdgcn_global_load_lds(                                          \
        (const __attribute__((address_space(1))) uint32_t*)(g),                \
        (__attribute__((address_space(3))) uint32_t*)(l), 16, 0, 0)

// ============ GEMM: C[M,N] = act((A[M,K] @ B[N,K]^T + bias)*oscale) ============
// tile 128x64, BK=32, 4 waves 2x2. B is always fp32 (reg-staged + cvt_pk).
// AFP32=1: A fp32 reg-staged, double-buffered LDS, next-step prefetch.
// AFP32=0: A bf16 via global_load_lds (single-buffer, proven path).
// PAIR=1: blockIdx.z in {0,1} selects operand set (q-proj / k-proj merge).
// PAIR=0: blockIdx.z batches via element strides sAb/sBb/sCb.
#define GBM 128
#define GBN 64
#define GBK 32

template<int AFP32, int PAIR>
__global__ __launch_bounds__(256)
void gemm_f(const void* __restrict__ Ap, const float* __restrict__ Bp,
            const float* __restrict__ bias, short* __restrict__ Cp,
            const void* __restrict__ Ap2, const float* __restrict__ Bp2,
            short* __restrict__ Cp2,
            int M, int N, int K, int relu, float os1, float os2,
            long sAb, long sBb, long sCb)
{
    __shared__ short As[(AFP32 ? 2 : 1)][GBM * GBK];
    __shared__ short Bs[2][GBN * GBK];
    const int tid = threadIdx.x;
    const int l   = tid & 63, w = tid >> 6;
    const int l15 = l & 15,  l4 = l >> 4;
    const int wrow = w >> 1, wcol = w & 1;
    const int m0 = blockIdx.y * GBM, n0 = blockIdx.x * GBN;
    const int z  = blockIdx.z;

    const void*  Aab;
    const float* Bm;
    short*       C;
    float        oscale;
    if (PAIR) {
        Aab = z ? Ap2 : Ap;  Bm = z ? Bp2 : Bp;  C = z ? Cp2 : Cp;
        oscale = z ? os2 : os1;
    } else {
        Aab = (const char*)Ap + (long)z * sAb * (AFP32 ? 4 : 2);
        Bm  = Bp + (long)z * sBb;
        C   = Cp + (long)z * sCb;
        oscale = os1;
    }

    f32x4 acc[4][2] = {};

    // --- staging geometry ---
    // A fp32: thread -> row=tid>>1 (128), half=tid&1 (16 cols each)
    const int arow = tid >> 1, ahalf = tid & 1;
    // B fp32: thread -> row=tid>>2 (64), q=tid&3 (8 cols each)
    const int brow = tid >> 2, bq = tid & 3;

    if (AFP32) {
        const float* A = (const float*)Aab;
        // prologue: load + stage K-step 0 into buf 0
        float4 a0, a1, a2, a3, b0, b1;
        {
            const float* asrc = A + (size_t)(m0 + arow) * K + ahalf * 16;
            a0 = ((const float4*)asrc)[0]; a1 = ((const float4*)asrc)[1];
            a2 = ((const float4*)asrc)[2]; a3 = ((const float4*)asrc)[3];
            const float* bsrc = Bm + (size_t)(n0 + brow) * K + bq * 8;
            b0 = ((const float4*)bsrc)[0]; b1 = ((const float4*)bsrc)[1];
        }
        {
            uint4 u0 = {cvtpk_bf16(a0.x,a0.y), cvtpk_bf16(a0.z,a0.w),
                        cvtpk_bf16(a1.x,a1.y), cvtpk_bf16(a1.z,a1.w)};
            uint4 u1 = {cvtpk_bf16(a2.x,a2.y), cvtpk_bf16(a2.z,a2.w),
                        cvtpk_bf16(a3.x,a3.y), cvtpk_bf16(a3.z,a3.w)};
            *(uint4*)&As[0][arow * 32 + ahalf * 16]     = u0;
            *(uint4*)&As[0][arow * 32 + ahalf * 16 + 8] = u1;
            uint4 ub = {cvtpk_bf16(b0.x,b0.y), cvtpk_bf16(b0.z,b0.w),
                        cvtpk_bf16(b1.x,b1.y), cvtpk_bf16(b1.z,b1.w)};
            *(uint4*)&Bs[0][brow * 32 + bq * 8] = ub;
        }
        __syncthreads();

        const int nsteps = K / GBK;
        for (int t = 0; t < nsteps; ++t) {
            const int cur = t & 1;
            // issue next-step global loads (overlap with MFMAs below)
            if (t + 1 < nsteps) {
                const float* asrc = A + (size_t)(m0 + arow) * K + (t + 1) * GBK + ahalf * 16;
                a0 = ((const float4*)asrc)[0]; a1 = ((const float4*)asrc)[1];
                a2 = ((const float4*)asrc)[2]; a3 = ((const float4*)asrc)[3];
                const float* bsrc = Bm + (size_t)(n0 + brow) * K + (t + 1) * GBK + bq * 8;
                b0 = ((const float4*)bsrc)[0]; b1 = ((const float4*)bsrc)[1];
            }
            bf16x8 af[4], bfr[2];
            #pragma unroll
            for (int mi = 0; mi < 4; ++mi)
                af[mi] = *(const bf16x8*)&As[cur][(wrow * 64 + mi * 16 + l15) * GBK + l4 * 8];
            #pragma unroll
            for (int ni = 0; ni < 2; ++ni)
                bfr[ni] = *(const bf16x8*)&Bs[cur][(wcol * 32 + ni * 16 + l15) * GBK + l4 * 8];
            #pragma unroll
            for (int mi = 0; mi < 4; ++mi)
                #pragma unroll
                for (int ni = 0; ni < 2; ++ni)
                    acc[mi][ni] = __builtin_amdgcn_mfma_f32_16x16x32_bf16(af[mi], bfr[ni], acc[mi][ni], 0, 0, 0);
            // stage next step into other buffer (waits on loads; overlapped w/ MFMA issue)
            if (t + 1 < nsteps) {
                uint4 u0 = {cvtpk_bf16(a0.x,a0.y), cvtpk_bf16(a0.z,a0.w),
                            cvtpk_bf16(a1.x,a1.y), cvtpk_bf16(a1.z,a1.w)};
                uint4 u1 = {cvtpk_bf16(a2.x,a2.y), cvtpk_bf16(a2.z,a2.w),
                            cvtpk_bf16(a3.x,a3.y), cvtpk_bf16(a3.z,a3.w)};
                *(uint4*)&As[cur ^ 1][arow * 32 + ahalf * 16]     = u0;
                *(uint4*)&As[cur ^ 1][arow * 32 + ahalf * 16 + 8] = u1;
                uint4 ub = {cvtpk_bf16(b0.x,b0.y), cvtpk_bf16(b0.z,b0.w),
                            cvtpk_bf16(b1.x,b1.y), cvtpk_bf16(b1.z,b1.w)};
                *(uint4*)&Bs[cur ^ 1][brow * 32 + bq * 8] = ub;
            }
            __syncthreads();
        }
    } else {
        const short* A = (const short*)Aab;
        for (int k0 = 0; k0 < K; k0 += GBK) {
            {
                int ch = tid;
                GLD_LDS16(A + (size_t)(m0 + (ch >> 2)) * K + k0 + (ch & 3) * 8, &As[0][ch * 8]);
                ch = tid + 256;
                GLD_LDS16(A + (size_t)(m0 + (ch >> 2)) * K + k0 + (ch & 3) * 8, &As[0][ch * 8]);
            }
            {
                const float* bsrc = Bm + (size_t)(n0 + brow) * K + k0 + bq * 8;
                float4 b0 = ((const float4*)bsrc)[0], b1 = ((const float4*)bsrc)[1];
                uint4 ub = {cvtpk_bf16(b0.x,b0.y), cvtpk_bf16(b0.z,b0.w),
                            cvtpk_bf16(b1.x,b1.y), cvtpk_bf16(b1.z,b1.w)};
                *(uint4*)&Bs[0][brow * 32 + bq * 8] = ub;
            }
            __syncthreads();
            bf16x8 af[4], bfr[2];
            #pragma unroll
            for (int mi = 0; mi < 4; ++mi)
                af[mi] = *(const bf16x8*)&As[0][(wrow * 64 + mi * 16 + l15) * GBK + l4 * 8];
            #pragma unroll
            for (int ni = 0; ni < 2; ++ni)
                bfr[ni] = *(const bf16x8*)&Bs[0][(wcol * 32 + ni * 16 + l15) * GBK + l4 * 8];
            #pragma unroll
            for (int mi = 0; mi < 4; ++mi)
                #pragma unroll
                for (int ni = 0; ni < 2; ++ni)
                    acc[mi][ni] = __builtin_amdgcn_mfma_f32_16x16x32_bf16(af[mi], bfr[ni], acc[mi][ni], 0, 0, 0);
            __syncthreads();
        }
    }

    #pragma unroll
    for (int mi = 0; mi < 4; ++mi) {
        #pragma unroll
        for (int ni = 0; ni < 2; ++ni) {
            int col = n0 + wcol * 32 + ni * 16 + l15;
            float bb = bias ? bias[col] : 0.0f;
            #pragma unroll
            for (int r = 0; r < 4; ++r) {
                int row = m0 + wrow * 64 + mi * 16 + l4 * 4 + r;
                float vv = (acc[mi][ni][r] + bb) * oscale;
                if (relu) vv = fmaxf(vv, 0.0f);
                C[(size_t)row * N + col] = f2b(vv);
            }
        }
    }
}

// ============ swapped-QK^T flash attention, log2-domain softmax, dbuf LDS ============
// grid (SEQ/64, NH, NB), 256 threads = 4 waves; wave w owns q-rows blk*64 + w*16 + (l&15)
// kp comes PRE-SCALED by (1/sqrt(512))*log2(e) from its projection GEMM.
__global__ __launch_bounds__(256, 4)
void attn_mfma4(const short* __restrict__ qp, const short* __restrict__ kp,
                const short* __restrict__ vt, const int* __restrict__ mask,
                short* __restrict__ attn)
{
    __shared__ short Kb[2][64 * 64];             // K tile  [k-row][d], swizzled rows
    __shared__ short Vb[2][64 * 64];             // Vt tile [d-row][k], swizzled rows
    __shared__ __align__(16) char Ps[4 * 2048];  // per-wave P[16q][64k] bf16, XOR-swizzled

    const int tid = threadIdx.x;
    const int l   = tid & 63, w = tid >> 6;
    const int l15 = l & 15,  l4 = l >> 4;
    const int h   = blockIdx.y, b = blockIdx.z;
    const int qrow = blockIdx.x * 64 + w * 16 + l15;
    const size_t baseqk = ((size_t)b * SEQ) * DMODEL + h * HD;
    const size_t basev  = ((size_t)b * DMODEL + h * HD) * SEQ;

    const int ch0 = tid, ch1 = tid + 256;
    const int r0 = ch0 >> 3, r1 = ch1 >> 3;
    const int so0 = (((ch0 & 7) * 16) ^ ((r0 & 7) << 4)) >> 1;   // pre-swizzled src (rule #21)
    const int so1 = (((ch1 & 7) * 16) ^ ((r1 & 7) << 4)) >> 1;
    const short* kph = kp + baseqk;
    const short* vth = vt + basev;
    const int*   mrow = mask + b * SEQ;

#define STAGE(t, bufi) do {                                                          \
        GLD_LDS16(kph + (size_t)((t) * 64 + r0) * DMODEL + so0, &Kb[bufi][ch0 * 8]); \
        GLD_LDS16(kph + (size_t)((t) * 64 + r1) * DMODEL + so1, &Kb[bufi][ch1 * 8]); \
        GLD_LDS16(vth + (size_t)r0 * SEQ + (t) * 64 + so0,      &Vb[bufi][ch0 * 8]); \
        GLD_LDS16(vth + (size_t)r1 * SEQ + (t) * 64 + so1,      &Vb[bufi][ch1 * 8]); \
    } while (0)

    bf16x8 qf0, qf1;
    {
        const short* qr = qp + baseqk + (size_t)qrow * DMODEL + l4 * 8;
        qf0 = *(const bf16x8*)qr;
        qf1 = *(const bf16x8*)(qr + 32);
    }

    STAGE(0, 0);
    __syncthreads();   // vmcnt(0) drain: tile 0 resident

    float m_ = -1.0e30f, l_ = 0.0f;
    f32x4 oacc[4] = {};                          // O^T[d][q]: d = db*16 + l4*4 + r, q = l15
    char* myPs = Ps + w * 2048;
    const int swp = (l15 & 7) << 4;

    for (int t = 0; t < 16; ++t) {
        const int cur = t & 1;
        if (t < 15) STAGE(t + 1, cur ^ 1);       // prefetch overlaps compute

        // ---- S^T[k][q] = K·Q^T from LDS (s is already logits*log2e) ----
        f32x4 s[4];
        __builtin_amdgcn_s_setprio(1);
        #pragma unroll
        for (int c = 0; c < 4; ++c) {
            int r = c * 16 + l15;
            const short* kb = &Kb[cur][r * 64];
            int o0 = ((l4 * 16) ^ ((r & 7) << 4)) >> 1;
            int o1 = ((64 + l4 * 16) ^ ((r & 7) << 4)) >> 1;
            bf16x8 kf0 = *(const bf16x8*)(kb + o0);
            bf16x8 kf1 = *(const bf16x8*)(kb + o1);
            f32x4 z = {};
            z = __builtin_amdgcn_mfma_f32_16x16x32_bf16(kf0, qf0, z, 0, 0, 0);
            z = __builtin_amdgcn_mfma_f32_16x16x32_bf16(kf1, qf1, z, 0, 0, 0);
            s[c] = z;
        }
        __builtin_amdgcn_s_setprio(0);

        // ---- mask: s -> -1e30 where masked (k = t*64 + c*16 + l4*4 + r) ----
        #pragma unroll
        for (int c = 0; c < 4; ++c) {
            int4 mi = *(const int4*)&mrow[t * 64 + c * 16 + l4 * 4];
            s[c][0] = mi.x ? -1.0e30f : s[c][0];
            s[c][1] = mi.y ? -1.0e30f : s[c][1];
            s[c][2] = mi.z ? -1.0e30f : s[c][2];
            s[c][3] = mi.w ? -1.0e30f : s[c][3];
        }

        // ---- online softmax in exp2 domain, wave-uniform defer-max (T13) ----
        float x0 = fmaxf(fmaxf(s[0][0], s[0][1]), fmaxf(s[0][2], s[0][3]));
        float x1 = fmaxf(fmaxf(s[1][0], s[1][1]), fmaxf(s[1][2], s[1][3]));
        float x2 = fmaxf(fmaxf(s[2][0], s[2][1]), fmaxf(s[2][2], s[2][3]));
        float x3 = fmaxf(fmaxf(s[3][0], s[3][1]), fmaxf(s[3][2], s[3][3]));
        float pm = fmaxf(fmaxf(x0, x1), fmaxf(x2, x3));
        pm = fmaxf(pm, __shfl_xor(pm, 16));
        pm = fmaxf(pm, __shfl_xor(pm, 32));
        if (!__all(pm <= m_ + 8.0f)) {           // wave-uniform rescale
            float mnew = fmaxf(m_, pm);
            float al   = exp2f(m_ - mnew);
            l_ *= al;
            #pragma unroll
            for (int db = 0; db < 4; ++db) {
                oacc[db][0] *= al; oacc[db][1] *= al;
                oacc[db][2] *= al; oacc[db][3] *= al;
            }
            m_ = mnew;
        }
        float p[16];
        #pragma unroll
        for (int c = 0; c < 4; ++c)
            #pragma unroll
            for (int r = 0; r < 4; ++r)
                p[c * 4 + r] = exp2f(s[c][r] - m_);
        float rsum = ((p[0] + p[1]) + (p[2] + p[3])) + ((p[4] + p[5]) + (p[6] + p[7]))
                   + ((p[8] + p[9]) + (p[10] + p[11])) + ((p[12] + p[13]) + (p[14] + p[15]));
        rsum += __shfl_xor(rsum, 16);
        rsum += __shfl_xor(rsum, 32);
        l_ += rsum;

        // ---- P pack (cvt_pk) + exchange via wave-private swizzled LDS ----
        #pragma unroll
        for (int c = 0; c < 4; ++c) {
            uint2 u;
            u.x = cvtpk_bf16(p[c * 4 + 0], p[c * 4 + 1]);
            u.y = cvtpk_bf16(p[c * 4 + 2], p[c * 4 + 3]);
            *(uint2*)(myPs + ((l15 * 128 + c * 32 + l4 * 8) ^ swp)) = u;
        }
        bf16x8 pf0 = *(const bf16x8*)(myPs + ((l15 * 128 +  0 + l4 * 16) ^ swp));
        bf16x8 pf1 = *(const bf16x8*)(myPs + ((l15 * 128 + 64 + l4 * 16) ^ swp));

        // ---- O^T += Vt·P^T from LDS ----
        __builtin_amdgcn_s_setprio(1);
        #pragma unroll
        for (int db = 0; db < 4; ++db) {
            int d = db * 16 + l15;
            const short* vb = &Vb[cur][d * 64];
            int o0 = ((l4 * 16) ^ ((d & 7) << 4)) >> 1;
            int o1 = ((64 + l4 * 16) ^ ((d & 7) << 4)) >> 1;
            bf16x8 vf0 = *(const bf16x8*)(vb + o0);
            bf16x8 vf1 = *(const bf16x8*)(vb + o1);
            oacc[db] = __builtin_amdgcn_mfma_f32_16x16x32_bf16(vf0, pf0, oacc[db], 0, 0, 0);
            oacc[db] = __builtin_amdgcn_mfma_f32_16x16x32_bf16(vf1, pf1, oacc[db], 0, 0, 0);
        }
        __builtin_amdgcn_s_setprio(0);
        __syncthreads();   // tile t+1 landed (vmcnt drain) + closes buf[cur] reads
    }
#undef STAGE

    float inv = (m_ > -1.0e29f) ? 1.0f / l_ : 0.0f;   // all-masked row -> 0 (ref: NaN->0)
    #pragma unroll
    for (int db = 0; db < 4; ++db) {
        short4 o;
        o.x = f2b(oacc[db][0] * inv);
        o.y = f2b(oacc[db][1] * inv);
        o.z = f2b(oacc[db][2] * inv);
        o.w = f2b(oacc[db][3] * inv);
        *(short4*)(attn + baseqk + (size_t)qrow * DMODEL + db * 16 + l4 * 4) = o;
    }
}

// ============ fused add + LayerNorm (bf16 in, bf16 or fp32 out) ============
__global__ __launch_bounds__(256)
void add_ln_b(const short* __restrict__ A, const short* __restrict__ Bv,
              const float* __restrict__ g, const float* __restrict__ beta,
              short* __restrict__ outb, float* __restrict__ outf)
{
    const int row = blockIdx.x;
    const int tid = threadIdx.x;
    const size_t off = (size_t)row * DMODEL;
    short2 a2 = *(const short2*)&A[off + tid * 2];
    short2 c2 = *(const short2*)&Bv[off + tid * 2];
    float x0 = b2f(a2.x) + b2f(c2.x);
    float x1 = b2f(a2.y) + b2f(c2.y);
    float s  = x0 + x1;
    float sq = x0 * x0 + x1 * x1;
    #pragma unroll
    for (int o = 1; o < 64; o <<= 1) {
        s  += __shfl_xor(s,  o);
        sq += __shfl_xor(sq, o);
    }
    __shared__ float ls[4], lq[4];
    const int w = tid >> 6;
    if ((tid & 63) == 0) { ls[w] = s; lq[w] = sq; }
    __syncthreads();
    s  = ls[0] + ls[1] + ls[2] + ls[3];
    sq = lq[0] + lq[1] + lq[2] + lq[3];
    const float mean = s * (1.0f / DMODEL);
    const float var  = sq * (1.0f / DMODEL) - mean * mean;
    const float rs   = rsqrtf(var + 1e-5f);
    const int c0 = tid * 2, c1 = tid * 2 + 1;
    float y0 = (x0 - mean) * rs * g[c0] + beta[c0];
    float y1 = (x1 - mean) * rs * g[c1] + beta[c1];
    if (outb) {
        short2 o; o.x = f2b(y0); o.y = f2b(y1);
        *(short2*)&outb[off + tid * 2] = o;
    } else {
        float2 o; o.x = y0; o.y = y1;
        *(float2*)&outf[off + tid * 2] = o;
    }
}

// ============ launch ============
extern "C" void kernel_launch(void* const* d_in, const int* in_sizes, int n_in,
                              void* d_out, int out_size, void* d_ws, size_t ws_size,
                              hipStream_t stream)
{
    const float* q    = (const float*)d_in[0];
    const float* k    = (const float*)d_in[1];
    const float* v    = (const float*)d_in[2];
    const int*   mask = (const int*)  d_in[3];
    const float* Wq   = (const float*)d_in[4];
    const float* Wk   = (const float*)d_in[5];
    const float* Wv   = (const float*)d_in[6];
    const float* Wo   = (const float*)d_in[7];
    const float* bo   = (const float*)d_in[8];
    const float* g1   = (const float*)d_in[9];
    const float* b1   = (const float*)d_in[10];
    const float* g2   = (const float*)d_in[11];
    const float* bt2  = (const float*)d_in[12];
    float* out = (float*)d_out;

    short* ws = (short*)d_ws;
    const size_t SLOT = (size_t)R_TOT * DMODEL;
    short* qpb = ws;
    short* kpb = qpb + SLOT;
    short* vtb = kpb + SLOT;     // vt[b][dmodel][SEQ]
    short* at  = vtb + SLOT;
    short* y   = at + SLOT;
    short* z   = y + SLOT;

    // kp pre-scaled by (1/sqrt(512)) * log2(e) for exp2-domain softmax
    const float kscale = 0.06375871530f;

    // merged q-proj (z=0) + k-proj (z=1), fp32 operands converted inline
    dim3 gqk(DMODEL / GBN, R_TOT / GBM, 2);   // (8, 64, 2)
    gemm_f<1, 1><<<gqk, 256, 0, stream>>>(q, Wq, nullptr, qpb, k, Wk, kpb,
                                          R_TOT, DMODEL, DMODEL, 0, 1.0f, kscale,
                                          0, 0, 0);
    // vt[b] = Wv (512x512) @ v_b^T -> [DMODEL][SEQ] (coalesced transposed V-projection)
    dim3 gv(SEQ / GBN, DMODEL / GBM, NB);     // (16, 4, 8)
    gemm_f<1, 0><<<gv, 256, 0, stream>>>(Wv, v, nullptr, vtb, nullptr, nullptr, nullptr,
                                         DMODEL, SEQ, DMODEL, 0, 1.0f, 0.0f,
                                         0, (long)SEQ * DMODEL, (long)DMODEL * SEQ);

    attn_mfma4<<<dim3(SEQ / 64, NH, NB), 256, 0, stream>>>(qpb, kpb, vtb, mask, at);

    add_ln_b<<<R_TOT, 256, 0, stream>>>(qpb, at, g1, b1, y, nullptr);

    // out-proj: A = y (bf16, global_load_lds path), B = Wo fp32, +bias, relu
    dim3 gg(DMODEL / GBN, R_TOT / GBM, 1);    // (8, 64)
    gemm_f<0, 0><<<gg, 256, 0, stream>>>(y, Wo, bo, z, nullptr, nullptr, nullptr,
                                         R_TOT, DMODEL, DMODEL, 1, 1.0f, 0.0f,
                                         0, 0, 0);

    add_ln_b<<<R_TOT, 256, 0, stream>>>(y, z, g2, bt2, nullptr, out);
}